// Round 6
// baseline (206.515 us; speedup 1.0000x reference)
//
#include <hip/hip_runtime.h>
#include <hip/hip_bf16.h>

// IndexedLinear: out[n] = x[n] @ W[idx[n]]
// N=262144, D_IN=D_OUT=256, NUM_TYPES=16, fp32 in/out.
// Bucket rows by type -> grouped bf16-MFMA GEMM.
// Round 4: cross-tile software pipeline. Each block owns ~9 consecutive
// 32-row tiles; x-loads for tile i+1 are issued into registers before tile
// i's K-loop so HBM stays saturated through compute (duty-cycle fix; rounds
// 2-3 showed latency-bound at 2.2-2.5 TB/s regardless of occupancy).

#define NTYPES 16
#define TROWS 32
#define GRID_BLOCKS 1024

typedef __bf16 bf16x8 __attribute__((ext_vector_type(8)));
typedef float f32x4 __attribute__((ext_vector_type(4)));

static __device__ __forceinline__ unsigned int f2bf_pk(float a, float b) {
  unsigned int ua = __float_as_uint(a);
  unsigned int ub = __float_as_uint(b);
  ua = (ua + 0x7FFFu + ((ua >> 16) & 1u)) >> 16;  // RNE f32->bf16
  ub = (ub + 0x7FFFu + ((ub >> 16) & 1u)) >> 16;
  return ua | (ub << 16);
}

// meta layout (unsigned int):
// [0..15]  cnt
// [16..31] off   (exclusive prefix of cnt)
// [32..47] cursor (scatter write positions, starts = off)
// [48..64] tileStart (prefix of ceil(cnt/TROWS)), tileStart[16] = total tiles

__global__ void zero_meta_kernel(unsigned int* meta) {
  if (threadIdx.x < 128) meta[threadIdx.x] = 0;
}

__global__ void hist_kernel(const int* __restrict__ idx, int N,
                            unsigned int* __restrict__ meta) {
  __shared__ unsigned int h[NTYPES];
  if (threadIdx.x < NTYPES) h[threadIdx.x] = 0;
  __syncthreads();
  for (int n = blockIdx.x * 256 + threadIdx.x; n < N; n += gridDim.x * 256)
    atomicAdd(&h[idx[n] & 15], 1u);
  __syncthreads();
  if (threadIdx.x < NTYPES) atomicAdd(&meta[threadIdx.x], h[threadIdx.x]);
}

__global__ void prefix_kernel(unsigned int* meta) {
  if (threadIdx.x == 0) {
    unsigned int o = 0, ts = 0;
    for (int t = 0; t < NTYPES; t++) {
      meta[16 + t] = o;
      meta[32 + t] = o;
      meta[48 + t] = ts;
      o += meta[t];
      ts += (meta[t] + (TROWS - 1)) / TROWS;
    }
    meta[64] = ts;
  }
}

// One thread per tile: resolve (type, rowbase, nrows) once.
__global__ void tiles_kernel(const unsigned int* __restrict__ meta,
                             uint2* __restrict__ desc, int maxTiles) {
  __shared__ unsigned int ts[17], offs[16], cnts[16];
  if (threadIdx.x < 17) ts[threadIdx.x] = meta[48 + threadIdx.x];
  if (threadIdx.x < 16) {
    offs[threadIdx.x] = meta[16 + threadIdx.x];
    cnts[threadIdx.x] = meta[threadIdx.x];
  }
  __syncthreads();
  int tile = blockIdx.x * 256 + threadIdx.x;
  if (tile >= maxTiles) return;
  uint2 d = make_uint2(0u, 0u);
  if ((unsigned)tile < ts[16]) {
    int t = 0;
    while ((unsigned)tile >= ts[t + 1]) t++;
    unsigned int rowbase = offs[t] + ((unsigned)tile - ts[t]) * TROWS;
    unsigned int rem = offs[t] + cnts[t] - rowbase;
    unsigned int nrows = rem < (unsigned)TROWS ? rem : (unsigned)TROWS;
    d = make_uint2(rowbase, (unsigned)t | (nrows << 8));
  }
  desc[tile] = d;
}

__global__ void scatter_kernel(const int* __restrict__ idx, int N,
                               unsigned int* __restrict__ meta,
                               int* __restrict__ perm) {
  __shared__ unsigned int h[NTYPES];
  __shared__ unsigned int base[NTYPES];
  int b0 = blockIdx.x * 4096;
  if (threadIdx.x < NTYPES) h[threadIdx.x] = 0;
  __syncthreads();
  unsigned int lr[16];
  int tt[16];
#pragma unroll
  for (int i = 0; i < 16; i++) {
    int n = b0 + i * 256 + threadIdx.x;
    int t = (n < N) ? (idx[n] & 15) : 0;
    tt[i] = t;
    lr[i] = (n < N) ? atomicAdd(&h[t], 1u) : 0u;
  }
  __syncthreads();
  if (threadIdx.x < NTYPES)
    base[threadIdx.x] = atomicAdd(&meta[32 + threadIdx.x], h[threadIdx.x]);
  __syncthreads();
#pragma unroll
  for (int i = 0; i < 16; i++) {
    int n = b0 + i * 256 + threadIdx.x;
    if (n < N) perm[base[tt[i]] + lr[i]] = n;
  }
}

// Pack W[t][k][c] (fp32) -> Wp[(t*8+kblk)*256 + c][ks] (bf16).
__global__ void packW_kernel(const float* __restrict__ W,
                             unsigned short* __restrict__ Wp) {
  int id = blockIdx.x * 256 + threadIdx.x;  // (t*8+kblk)*256 + c, 32768 total
  int c = id & 255;
  int tk = id >> 8;  // t*8+kblk
  const float* src = W + (size_t)tk * 32 * 256 + c;
  unsigned int buf[16];
#pragma unroll
  for (int p = 0; p < 16; p++)
    buf[p] = f2bf_pk(src[(2 * p) * 256], src[(2 * p + 1) * 256]);
  uint4* d4 = (uint4*)(Wp + (size_t)id * 32);
#pragma unroll
  for (int p = 0; p < 4; p++)
    d4[p] = make_uint4(buf[4 * p], buf[4 * p + 1], buf[4 * p + 2], buf[4 * p + 3]);
}

// Pipelined grouped GEMM. Each block: tiles [base, base+tilesPerBlk).
// Per iteration: (1) stage-regs -> LDS (bf16), (2) barrier, (3) issue next
// tile's x loads + perm/desc prefetch, (4) K-loop (W streamed from L2),
// (5) stores, (6) barrier. x HBM loads are in flight across the whole
// compute phase of the previous tile.
__global__ __launch_bounds__(256, 4) void gemm_kernel(
    const float* __restrict__ x, const unsigned short* __restrict__ Wp,
    const int* __restrict__ perm, const uint2* __restrict__ desc,
    float* __restrict__ out, int tilesPerBlk, int maxTiles) {
  __shared__ uint4 ldsx[TROWS * 32];  // 32 rows x 256 k (bf16) = 16 KiB
  __shared__ int permS[TROWS];

  int base = blockIdx.x * tilesPerBlk;
  if (base >= maxTiles) return;

  int tid = threadIdx.x;
  int l = tid & 63, w = tid >> 6;
  int lm = l & 15, lh = l >> 4;
  int r = tid >> 3, q = tid & 7;  // staging: 8 threads per row, 4 kchunks each

  const uint4* Wp4 = (const uint4*)Wp;
  int clampT = maxTiles - 1;

  // ---- prologue: tile base+0 staged, perm for +1, descs for +0..+2 ----
  uint2 dscCur = desc[base];
  uint2 dscNext = desc[base + 1 <= clampT ? base + 1 : clampT];
  uint2 dscNext2 = desc[base + 2 <= clampT ? base + 2 : clampT];

  int prCur = 0, prNext = 0;
  {
    int nr = (int)(dscCur.y >> 8);
    if (r < nr) prCur = perm[dscCur.x + r];
  }
  {
    int nr = (int)(dscNext.y >> 8);
    if (tilesPerBlk > 1 && r < nr) prNext = perm[dscNext.x + r];
  }

  float4 st[8];
  {
    int nr = (int)(dscCur.y >> 8);
    if (r < nr) {
      const float4* xr = (const float4*)(x + (size_t)prCur * 256);
#pragma unroll
      for (int c0 = 0; c0 < 4; c0++) {
        st[2 * c0] = xr[(q * 4 + c0) * 2];
        st[2 * c0 + 1] = xr[(q * 4 + c0) * 2 + 1];
      }
    } else {
#pragma unroll
      for (int i = 0; i < 8; i++) st[i] = make_float4(0.f, 0.f, 0.f, 0.f);
    }
  }

  for (int it = 0; it < tilesPerBlk; ++it) {
    int tile = base + it;
    if (tile >= maxTiles) break;
    int nrowsC = (int)(dscCur.y >> 8);
    int tC = (int)(dscCur.y & 15u);

    // (1) stage regs -> LDS (fp32 -> bf16, swizzled), permS
    if (q == 0) permS[r] = prCur;
#pragma unroll
    for (int c0 = 0; c0 < 4; c0++) {
      int kchunk = q * 4 + c0;
      uint4 v;
      v.x = f2bf_pk(st[2 * c0].x, st[2 * c0].y);
      v.y = f2bf_pk(st[2 * c0].z, st[2 * c0].w);
      v.z = f2bf_pk(st[2 * c0 + 1].x, st[2 * c0 + 1].y);
      v.w = f2bf_pk(st[2 * c0 + 1].z, st[2 * c0 + 1].w);
      ldsx[r * 32 + (kchunk ^ (r & 7))] = v;
    }
    __syncthreads();

    // (3) issue next tile's x loads (addresses from prNext, already in regs)
    {
      int nrN = (int)(dscNext.y >> 8);
      if (it + 1 < tilesPerBlk && r < nrN) {
        const float4* xr = (const float4*)(x + (size_t)prNext * 256);
#pragma unroll
        for (int c0 = 0; c0 < 4; c0++) {
          st[2 * c0] = xr[(q * 4 + c0) * 2];
          st[2 * c0 + 1] = xr[(q * 4 + c0) * 2 + 1];
        }
      } else {
#pragma unroll
        for (int i = 0; i < 8; i++) st[i] = make_float4(0.f, 0.f, 0.f, 0.f);
      }
    }
    // perm prefetch for tile+2; desc prefetch for tile+3
    int prNext2 = 0;
    {
      int nr2 = (int)(dscNext2.y >> 8);
      if (it + 2 < tilesPerBlk && r < nr2) prNext2 = perm[dscNext2.x + r];
    }
    int i3 = base + it + 3;
    uint2 dscNext3 = desc[i3 <= clampT ? i3 : clampT];

    // (4) K-loop: W streamed from L2 (fully unrolled; compiler pipelines)
    f32x4 acc[2][4];
#pragma unroll
    for (int i = 0; i < 2; i++)
#pragma unroll
      for (int j = 0; j < 4; j++) acc[i][j] = (f32x4){0.f, 0.f, 0.f, 0.f};

    const uint4* Wt = Wp4 + (size_t)tC * 8 * 256 * 4;
#pragma unroll
    for (int kk = 0; kk < 8; kk++) {
      bf16x8 a0, a1, bb[4];
      {
        int r2 = lm;
        a0 = __builtin_bit_cast(bf16x8,
                                ldsx[r2 * 32 + ((kk * 4 + lh) ^ (r2 & 7))]);
      }
      {
        int r2 = 16 + lm;
        a1 = __builtin_bit_cast(bf16x8,
                                ldsx[r2 * 32 + ((kk * 4 + lh) ^ (r2 & 7))]);
      }
#pragma unroll
      for (int fn = 0; fn < 4; fn++) {
        int c = w * 64 + fn * 16 + lm;
        bb[fn] = __builtin_bit_cast(bf16x8, Wt[(size_t)(kk * 256 + c) * 4 + lh]);
      }
#pragma unroll
      for (int fn = 0; fn < 4; fn++) {
        acc[0][fn] = __builtin_amdgcn_mfma_f32_16x16x32_bf16(a0, bb[fn],
                                                             acc[0][fn], 0, 0, 0);
        acc[1][fn] = __builtin_amdgcn_mfma_f32_16x16x32_bf16(a1, bb[fn],
                                                             acc[1][fn], 0, 0, 0);
      }
    }

    // (5) stores: D layout col=lane&15, row=(lane>>4)*4+r_
#pragma unroll
    for (int fm = 0; fm < 2; fm++) {
#pragma unroll
      for (int r_ = 0; r_ < 4; r_++) {
        int rit = fm * 16 + lh * 4 + r_;
        if (rit < nrowsC) {
          int grow = permS[rit];
          float* orow = out + (size_t)grow * 256 + w * 64 + lm;
#pragma unroll
          for (int fn = 0; fn < 4; fn++) orow[fn * 16] = acc[fm][fn][r_];
        }
      }
    }
    __syncthreads();  // protect ldsx/permS before next iteration's stage

    // shift pipeline registers
    dscCur = dscNext;
    dscNext = dscNext2;
    dscNext2 = dscNext3;
    prCur = prNext;
    prNext = prNext2;
  }
}

extern "C" void kernel_launch(void* const* d_in, const int* in_sizes, int n_in,
                              void* d_out, int out_size, void* d_ws,
                              size_t ws_size, hipStream_t stream) {
  const float* x = (const float*)d_in[0];
  const int* idx = (const int*)d_in[1];
  const float* W = (const float*)d_in[2];
  float* out = (float*)d_out;
  int N = in_sizes[0] / 256;
  int maxTiles = N / TROWS + NTYPES;

  // ws layout: meta (512 B) | desc (maxTiles*8 B) | perm (N*4 B) | Wp (2 MiB)
  unsigned int* meta = (unsigned int*)d_ws;
  uint2* desc = (uint2*)((char*)d_ws + 512);
  int* perm = (int*)((char*)d_ws + 512 + (size_t)maxTiles * 8);
  unsigned short* Wp =
      (unsigned short*)((char*)d_ws + 512 + (size_t)maxTiles * 8 +
                        (size_t)N * 4);

  zero_meta_kernel<<<1, 128, 0, stream>>>(meta);
  hist_kernel<<<256, 256, 0, stream>>>(idx, N, meta);
  prefix_kernel<<<1, 64, 0, stream>>>(meta);
  packW_kernel<<<128, 256, 0, stream>>>(W, Wp);
  tiles_kernel<<<(maxTiles + 255) / 256, 256, 0, stream>>>(meta, desc,
                                                           maxTiles);
  int nScatter = (N + 4095) / 4096;
  scatter_kernel<<<nScatter, 256, 0, stream>>>(idx, N, meta, perm);

  int grid = GRID_BLOCKS < maxTiles ? GRID_BLOCKS : maxTiles;
  int tilesPerBlk = (maxTiles + grid - 1) / grid;
  gemm_kernel<<<grid, 256, 0, stream>>>(x, Wp, perm, desc, out, tilesPerBlk,
                                        maxTiles);
}

// Round 7
// 185.134 us; speedup vs baseline: 1.1155x; 1.1155x over previous
//
#include <hip/hip_runtime.h>
#include <hip/hip_bf16.h>

// IndexedLinear: out[n] = x[n] @ W[idx[n]]
// N=262144, D_IN=D_OUT=256, NUM_TYPES=16, fp32 in/out.
// Bucket rows by type -> grouped bf16-MFMA GEMM.
// Round 5: stage x via global_load_lds (async, no VGPR round-trip) into
// double-buffered fp32 LDS tiles; 2-phase pipeline (stage i+1 || compute i,
// one vmcnt(0)+barrier per tile). Rounds 2-4 showed VGPR-staged pipelines get
// sunk by the compiler (VGPR=64 proof) -> stuck at 2.5 TB/s latency-bound.

#define NTYPES 16
#define TROWS 32
#define GRID_BLOCKS 512

typedef __bf16 bf16x8 __attribute__((ext_vector_type(8)));
typedef float f32x4 __attribute__((ext_vector_type(4)));

static __device__ __forceinline__ unsigned int f2bf_pk(float a, float b) {
  unsigned int ua = __float_as_uint(a);
  unsigned int ub = __float_as_uint(b);
  ua = (ua + 0x7FFFu + ((ua >> 16) & 1u)) >> 16;  // RNE f32->bf16
  ub = (ub + 0x7FFFu + ((ub >> 16) & 1u)) >> 16;
  return ua | (ub << 16);
}

static __device__ __forceinline__ void load16_lds(const float* g, float* l) {
  __builtin_amdgcn_global_load_lds(
      (const __attribute__((address_space(1))) unsigned int*)g,
      (__attribute__((address_space(3))) unsigned int*)l, 16, 0, 0);
}

// meta layout (unsigned int):
// [0..15] cnt | [16..31] off | [32..47] cursor | [48..64] tileStart prefix

__global__ void zero_meta_kernel(unsigned int* meta) {
  if (threadIdx.x < 128) meta[threadIdx.x] = 0;
}

__global__ void hist_kernel(const int* __restrict__ idx, int N,
                            unsigned int* __restrict__ meta) {
  __shared__ unsigned int h[NTYPES];
  if (threadIdx.x < NTYPES) h[threadIdx.x] = 0;
  __syncthreads();
  for (int n = blockIdx.x * 256 + threadIdx.x; n < N; n += gridDim.x * 256)
    atomicAdd(&h[idx[n] & 15], 1u);
  __syncthreads();
  if (threadIdx.x < NTYPES) atomicAdd(&meta[threadIdx.x], h[threadIdx.x]);
}

__global__ void prefix_kernel(unsigned int* meta) {
  if (threadIdx.x == 0) {
    unsigned int o = 0, ts = 0;
    for (int t = 0; t < NTYPES; t++) {
      meta[16 + t] = o;
      meta[32 + t] = o;
      meta[48 + t] = ts;
      o += meta[t];
      ts += (meta[t] + (TROWS - 1)) / TROWS;
    }
    meta[64] = ts;
  }
}

__global__ void tiles_kernel(const unsigned int* __restrict__ meta,
                             uint2* __restrict__ desc, int maxTiles) {
  __shared__ unsigned int ts[17], offs[16], cnts[16];
  if (threadIdx.x < 17) ts[threadIdx.x] = meta[48 + threadIdx.x];
  if (threadIdx.x < 16) {
    offs[threadIdx.x] = meta[16 + threadIdx.x];
    cnts[threadIdx.x] = meta[threadIdx.x];
  }
  __syncthreads();
  int tile = blockIdx.x * 256 + threadIdx.x;
  if (tile >= maxTiles) return;
  uint2 d = make_uint2(0u, 0u);
  if ((unsigned)tile < ts[16]) {
    int t = 0;
    while ((unsigned)tile >= ts[t + 1]) t++;
    unsigned int rowbase = offs[t] + ((unsigned)tile - ts[t]) * TROWS;
    unsigned int rem = offs[t] + cnts[t] - rowbase;
    unsigned int nrows = rem < (unsigned)TROWS ? rem : (unsigned)TROWS;
    d = make_uint2(rowbase, (unsigned)t | (nrows << 8));
  }
  desc[tile] = d;
}

__global__ void scatter_kernel(const int* __restrict__ idx, int N,
                               unsigned int* __restrict__ meta,
                               int* __restrict__ perm) {
  __shared__ unsigned int h[NTYPES];
  __shared__ unsigned int base[NTYPES];
  int b0 = blockIdx.x * 4096;
  if (threadIdx.x < NTYPES) h[threadIdx.x] = 0;
  __syncthreads();
  unsigned int lr[16];
  int tt[16];
#pragma unroll
  for (int i = 0; i < 16; i++) {
    int n = b0 + i * 256 + threadIdx.x;
    int t = (n < N) ? (idx[n] & 15) : 0;
    tt[i] = t;
    lr[i] = (n < N) ? atomicAdd(&h[t], 1u) : 0u;
  }
  __syncthreads();
  if (threadIdx.x < NTYPES)
    base[threadIdx.x] = atomicAdd(&meta[32 + threadIdx.x], h[threadIdx.x]);
  __syncthreads();
#pragma unroll
  for (int i = 0; i < 16; i++) {
    int n = b0 + i * 256 + threadIdx.x;
    if (n < N) perm[base[tt[i]] + lr[i]] = n;
  }
}

// Pack W[t][k][c] (fp32) -> Wp[(t*8+kblk)*256 + c][ks] (bf16).
__global__ void packW_kernel(const float* __restrict__ W,
                             unsigned short* __restrict__ Wp) {
  int id = blockIdx.x * 256 + threadIdx.x;  // (t*8+kblk)*256 + c
  int c = id & 255;
  int tk = id >> 8;
  const float* src = W + (size_t)tk * 32 * 256 + c;
  unsigned int buf[16];
#pragma unroll
  for (int p = 0; p < 16; p++)
    buf[p] = f2bf_pk(src[(2 * p) * 256], src[(2 * p + 1) * 256]);
  uint4* d4 = (uint4*)(Wp + (size_t)id * 32);
#pragma unroll
  for (int p = 0; p < 4; p++)
    d4[p] = make_uint4(buf[4 * p], buf[4 * p + 1], buf[4 * p + 2], buf[4 * p + 3]);
}

// 2-phase pipelined grouped GEMM, async staging.
// Per tile-iteration: STAGE(buf^1, tile+1) via global_load_lds ->
// compute tile from ldsx[buf] (fp32->bf16 at fragment build) -> stores ->
// __syncthreads (vmcnt(0)+barrier drains the prefetch) -> flip.
// LDS x-tile swizzle: LDS chunk m of row r holds source chunk m^(r&7)
// (pre-swizzled per-lane SOURCE, linear dest -- global_load_lds rule).
__global__ __launch_bounds__(256, 2) void gemm_kernel(
    const float* __restrict__ x, const unsigned short* __restrict__ Wp,
    const int* __restrict__ perm, const uint2* __restrict__ desc,
    float* __restrict__ out, int maxTiles) {
  __shared__ float ldsx[2][TROWS * 256];  // 2 x 32 KiB fp32
  __shared__ int permS[2][TROWS];

  // balanced 16/17-tile spans of consecutive tiles
  int tpb = maxTiles / GRID_BLOCKS;
  int rem = maxTiles - tpb * GRID_BLOCKS;
  int b = blockIdx.x;
  int base = b * tpb + (b < rem ? b : rem);
  int cnt = tpb + (b < rem ? 1 : 0);
  if (cnt <= 0) return;

  int tid = threadIdx.x;
  int l = tid & 63, w = tid >> 6;
  int lm = l & 15, lh = l >> 4;
  int clampT = maxTiles - 1;
  int myrow = w * 8 + (l & 7);  // row this lane prefetches perm for

  uint2 dscC = desc[base];
  uint2 dscN = desc[base + 1 <= clampT ? base + 1 : clampT];
  uint2 dscN2 = desc[base + 2 <= clampT ? base + 2 : clampT];

  int prCur, prNxt;
  {
    int nr = (int)(dscC.y >> 8);
    prCur = (myrow < nr) ? perm[dscC.x + myrow] : 0;
  }
  {
    int nr = (int)(dscN.y >> 8);
    prNxt = (cnt > 1 && myrow < nr) ? perm[dscN.x + myrow] : 0;
  }

  // prologue: permS[0] + stage tile base into buf 0
  if (l < 8) permS[0][w * 8 + l] = prCur;
#pragma unroll
  for (int j = 0; j < 8; ++j) {
    int prj = __shfl(prCur, j);
    const float* src = x + (size_t)prj * 256 + ((l ^ j) << 2);
    load16_lds(src, &ldsx[0][(w * 8 + j) * 256]);
  }
  __syncthreads();

  int buf = 0;
  const uint4* Wp4 = (const uint4*)Wp;

  for (int it = 0; it < cnt; ++it) {
    int nrowsC = (int)(dscC.y >> 8);
    int tC = (int)(dscC.y & 15u);

    // A. stage tile it+1 into buf^1 (async; drains at this iter's barrier)
    if (it + 1 < cnt) {
      if (l < 8) permS[buf ^ 1][w * 8 + l] = prNxt;
#pragma unroll
      for (int j = 0; j < 8; ++j) {
        int prj = __shfl(prNxt, j);
        const float* src = x + (size_t)prj * 256 + ((l ^ j) << 2);
        load16_lds(src, &ldsx[buf ^ 1][(w * 8 + j) * 256]);
      }
    }
    // B. register prefetch: perm for it+2, desc for it+3
    int prN2 = 0;
    if (it + 2 < cnt) {
      int nr2 = (int)(dscN2.y >> 8);
      if (myrow < nr2) prN2 = perm[dscN2.x + myrow];
    }
    int i3 = base + it + 3;
    uint2 dscN3 = desc[i3 <= clampT ? i3 : clampT];

    // C+D. compute + store current tile
    if (nrowsC > 0) {
      const uint4* Wt = Wp4 + (size_t)tC * 8 * 256 * 4;
      f32x4 acc[2][4];
#pragma unroll
      for (int i = 0; i < 2; i++)
#pragma unroll
        for (int j = 0; j < 4; j++) acc[i][j] = (f32x4){0.f, 0.f, 0.f, 0.f};

      bf16x8 bbc[4], bbn[4];
#pragma unroll
      for (int fn = 0; fn < 4; fn++) {
        int c = w * 64 + fn * 16 + lm;
        bbc[fn] = __builtin_bit_cast(bf16x8, Wt[(size_t)c * 4 + lh]);
      }

#pragma unroll
      for (int kk = 0; kk < 8; kk++) {
        bf16x8 a[2];
#pragma unroll
        for (int fm = 0; fm < 2; fm++) {
          int r2 = fm * 16 + lm;
          const float4* rowp = (const float4*)&ldsx[buf][r2 * 256];
          int c0 = kk * 8 + lh * 2;
          int s = r2 & 7;
          float4 f0 = rowp[c0 ^ s];
          float4 f1 = rowp[(c0 + 1) ^ s];
          uint4 v;
          v.x = f2bf_pk(f0.x, f0.y);
          v.y = f2bf_pk(f0.z, f0.w);
          v.z = f2bf_pk(f1.x, f1.y);
          v.w = f2bf_pk(f1.z, f1.w);
          a[fm] = __builtin_bit_cast(bf16x8, v);
        }
        if (kk < 7) {
#pragma unroll
          for (int fn = 0; fn < 4; fn++) {
            int c = w * 64 + fn * 16 + lm;
            bbn[fn] = __builtin_bit_cast(
                bf16x8, Wt[(size_t)((kk + 1) * 256 + c) * 4 + lh]);
          }
        }
#pragma unroll
        for (int fn = 0; fn < 4; fn++) {
          acc[0][fn] = __builtin_amdgcn_mfma_f32_16x16x32_bf16(
              a[0], bbc[fn], acc[0][fn], 0, 0, 0);
          acc[1][fn] = __builtin_amdgcn_mfma_f32_16x16x32_bf16(
              a[1], bbc[fn], acc[1][fn], 0, 0, 0);
        }
        if (kk < 7) {
#pragma unroll
          for (int fn = 0; fn < 4; fn++) bbc[fn] = bbn[fn];
        }
      }

      // stores: D layout col=lane&15, row=(lane>>4)*4+r_
#pragma unroll
      for (int fm = 0; fm < 2; fm++) {
#pragma unroll
        for (int r_ = 0; r_ < 4; r_++) {
          int rit = fm * 16 + lh * 4 + r_;
          if (rit < nrowsC) {
            int grow = permS[buf][rit];
            float* orow = out + (size_t)grow * 256 + w * 64 + lm;
#pragma unroll
            for (int fn = 0; fn < 4; fn++) orow[fn * 16] = acc[fm][fn][r_];
          }
        }
      }
    }

    __syncthreads();  // vmcnt(0)+lgkmcnt(0)+barrier: prefetch landed, LDS safe
    buf ^= 1;
    dscC = dscN;
    dscN = dscN2;
    dscN2 = dscN3;
    prNxt = prN2;
  }
}

extern "C" void kernel_launch(void* const* d_in, const int* in_sizes, int n_in,
                              void* d_out, int out_size, void* d_ws,
                              size_t ws_size, hipStream_t stream) {
  const float* x = (const float*)d_in[0];
  const int* idx = (const int*)d_in[1];
  const float* W = (const float*)d_in[2];
  float* out = (float*)d_out;
  int N = in_sizes[0] / 256;
  int maxTiles = N / TROWS + NTYPES;

  // ws layout: meta (512 B) | desc (maxTiles*8 B) | perm (N*4 B) | Wp (2 MiB)
  unsigned int* meta = (unsigned int*)d_ws;
  uint2* desc = (uint2*)((char*)d_ws + 512);
  int* perm = (int*)((char*)d_ws + 512 + (size_t)maxTiles * 8);
  unsigned short* Wp =
      (unsigned short*)((char*)d_ws + 512 + (size_t)maxTiles * 8 +
                        (size_t)N * 4);

  zero_meta_kernel<<<1, 128, 0, stream>>>(meta);
  hist_kernel<<<256, 256, 0, stream>>>(idx, N, meta);
  prefix_kernel<<<1, 64, 0, stream>>>(meta);
  packW_kernel<<<128, 256, 0, stream>>>(W, Wp);
  tiles_kernel<<<(maxTiles + 255) / 256, 256, 0, stream>>>(meta, desc,
                                                           maxTiles);
  int nScatter = (N + 4095) / 4096;
  scatter_kernel<<<nScatter, 256, 0, stream>>>(idx, N, meta, perm);

  gemm_kernel<<<GRID_BLOCKS, 256, 0, stream>>>(x, Wp, perm, desc, out,
                                               maxTiles);
}

// Round 9
// 163.694 us; speedup vs baseline: 1.2616x; 1.1310x over previous
//
#include <hip/hip_runtime.h>
#include <hip/hip_bf16.h>

// IndexedLinear: out[n] = x[n] @ W[idx[n]]
// N=262144, D_IN=D_OUT=256, NUM_TYPES=16, fp32 in/out.
// Round 7 = Round 6 with the dump-region OOB fixed (tid*64 floats overran a
// 16KB region -> corrupted perm -> device fault). Structure: counted-vmcnt
// barrier (stores stay in flight), W panel in 128 VGPRs, v_cvt_pk_bf16_f32,
// nontemporal stores, constant vmem queue shape (branchless dump stores).

#define NTYPES 16
#define TROWS 32
#define GRID_BLOCKS 512

typedef __bf16 bf16x8 __attribute__((ext_vector_type(8)));
typedef float f32x4 __attribute__((ext_vector_type(4)));

static __device__ __forceinline__ unsigned int f2bf_pk(float a, float b) {
  unsigned int ua = __float_as_uint(a);
  unsigned int ub = __float_as_uint(b);
  ua = (ua + 0x7FFFu + ((ua >> 16) & 1u)) >> 16;  // RNE f32->bf16
  ub = (ub + 0x7FFFu + ((ub >> 16) & 1u)) >> 16;
  return ua | (ub << 16);
}

static __device__ __forceinline__ unsigned int cvtpk(float a, float b) {
  unsigned int r;
  asm("v_cvt_pk_bf16_f32 %0, %1, %2" : "=v"(r) : "v"(a), "v"(b));
  return r;  // lo = bf16(a), hi = bf16(b), RNE
}

static __device__ __forceinline__ void load16_lds(const float* g, float* l) {
  __builtin_amdgcn_global_load_lds(
      (const __attribute__((address_space(1))) unsigned int*)g,
      (__attribute__((address_space(3))) unsigned int*)l, 16, 0, 0);
}

// meta layout (unsigned int):
// [0..15] cnt | [16..31] off | [32..47] cursor | [48..64] tileStart prefix

__global__ void zero_meta_kernel(unsigned int* meta) {
  if (threadIdx.x < 128) meta[threadIdx.x] = 0;
}

__global__ void hist_kernel(const int* __restrict__ idx, int N,
                            unsigned int* __restrict__ meta) {
  __shared__ unsigned int h[NTYPES];
  if (threadIdx.x < NTYPES) h[threadIdx.x] = 0;
  __syncthreads();
  for (int n = blockIdx.x * 256 + threadIdx.x; n < N; n += gridDim.x * 256)
    atomicAdd(&h[idx[n] & 15], 1u);
  __syncthreads();
  if (threadIdx.x < NTYPES) atomicAdd(&meta[threadIdx.x], h[threadIdx.x]);
}

__global__ void prefix_kernel(unsigned int* meta) {
  if (threadIdx.x == 0) {
    unsigned int o = 0, ts = 0;
    for (int t = 0; t < NTYPES; t++) {
      meta[16 + t] = o;
      meta[32 + t] = o;
      meta[48 + t] = ts;
      o += meta[t];
      ts += (meta[t] + (TROWS - 1)) / TROWS;
    }
    meta[64] = ts;
  }
}

__global__ void tiles_kernel(const unsigned int* __restrict__ meta,
                             uint2* __restrict__ desc, int maxTiles) {
  __shared__ unsigned int ts[17], offs[16], cnts[16];
  if (threadIdx.x < 17) ts[threadIdx.x] = meta[48 + threadIdx.x];
  if (threadIdx.x < 16) {
    offs[threadIdx.x] = meta[16 + threadIdx.x];
    cnts[threadIdx.x] = meta[threadIdx.x];
  }
  __syncthreads();
  int tile = blockIdx.x * 256 + threadIdx.x;
  if (tile >= maxTiles) return;
  uint2 d = make_uint2(0u, 0u);
  if ((unsigned)tile < ts[16]) {
    int t = 0;
    while ((unsigned)tile >= ts[t + 1]) t++;
    unsigned int rowbase = offs[t] + ((unsigned)tile - ts[t]) * TROWS;
    unsigned int rem = offs[t] + cnts[t] - rowbase;
    unsigned int nrows = rem < (unsigned)TROWS ? rem : (unsigned)TROWS;
    d = make_uint2(rowbase, (unsigned)t | (nrows << 8));
  }
  desc[tile] = d;
}

__global__ void scatter_kernel(const int* __restrict__ idx, int N,
                               unsigned int* __restrict__ meta,
                               int* __restrict__ perm) {
  __shared__ unsigned int h[NTYPES];
  __shared__ unsigned int base[NTYPES];
  int b0 = blockIdx.x * 4096;
  if (threadIdx.x < NTYPES) h[threadIdx.x] = 0;
  __syncthreads();
  unsigned int lr[16];
  int tt[16];
#pragma unroll
  for (int i = 0; i < 16; i++) {
    int n = b0 + i * 256 + threadIdx.x;
    int t = (n < N) ? (idx[n] & 15) : 0;
    tt[i] = t;
    lr[i] = (n < N) ? atomicAdd(&h[t], 1u) : 0u;
  }
  __syncthreads();
  if (threadIdx.x < NTYPES)
    base[threadIdx.x] = atomicAdd(&meta[32 + threadIdx.x], h[threadIdx.x]);
  __syncthreads();
#pragma unroll
  for (int i = 0; i < 16; i++) {
    int n = b0 + i * 256 + threadIdx.x;
    if (n < N) perm[base[tt[i]] + lr[i]] = n;
  }
}

// Pack W[t][k][c] (fp32) -> Wp[(t*8+kblk)*256 + c][ks] (bf16).
__global__ void packW_kernel(const float* __restrict__ W,
                             unsigned short* __restrict__ Wp) {
  int id = blockIdx.x * 256 + threadIdx.x;  // (t*8+kblk)*256 + c
  int c = id & 255;
  int tk = id >> 8;
  const float* src = W + (size_t)tk * 32 * 256 + c;
  unsigned int buf[16];
#pragma unroll
  for (int p = 0; p < 16; p++)
    buf[p] = f2bf_pk(src[(2 * p) * 256], src[(2 * p + 1) * 256]);
  uint4* d4 = (uint4*)(Wp + (size_t)id * 32);
#pragma unroll
  for (int p = 0; p < 4; p++)
    d4[p] = make_uint4(buf[4 * p], buf[4 * p + 1], buf[4 * p + 2], buf[4 * p + 3]);
}

// Pipelined grouped GEMM, counted-vmcnt barrier.
// vmem queue per iteration (in order): stage(8 global_load_lds) [, perm(1)]
// [, W reload(32, boundary only)] , stores(32 always, branchless dump).
// s_waitcnt vmcnt(32) + s_barrier: in-order vmem retirement means the 32
// newest (the stores) may stay outstanding while everything older (stage,
// perm, W) is provably retired -> store acks overlap next tile's compute.
__global__ __launch_bounds__(256, 2) void gemm_kernel(
    const float* __restrict__ x, const unsigned short* __restrict__ Wp,
    const int* __restrict__ perm, const uint2* __restrict__ desc,
    float* __restrict__ out, float* __restrict__ dump, int maxTiles) {
  __shared__ float ldsx[2][TROWS * 256];  // 2 x 32 KiB fp32
  __shared__ int permS[2][TROWS];

  // balanced 16/17-tile spans of consecutive tiles
  int tpb = maxTiles / GRID_BLOCKS;
  int rem = maxTiles - tpb * GRID_BLOCKS;
  int b = blockIdx.x;
  int base = b * tpb + (b < rem ? b : rem);
  int cnt = tpb + (b < rem ? 1 : 0);
  if (cnt <= 0) return;

  int tid = threadIdx.x;
  int l = tid & 63, w = tid >> 6;
  int lm = l & 15, lh = l >> 4;
  int clampT = maxTiles - 1;
  int myrow = w * 8 + (l & 7);

  uint2 dscC = desc[base];
  uint2 dscN = desc[base + 1 <= clampT ? base + 1 : clampT];
  uint2 dscN2 = desc[base + 2 <= clampT ? base + 2 : clampT];

  int prCur, prNxt;
  {
    int nr = (int)(dscC.y >> 8);
    prCur = (myrow < nr) ? perm[dscC.x + myrow] : 0;
  }
  {
    int nr = (int)(dscN.y >> 8);
    prNxt = (cnt > 1 && myrow < nr) ? perm[dscN.x + myrow] : 0;
  }

  // prologue: permS[0] + stage tile base into buf 0
  if (l < 8) permS[0][w * 8 + l] = prCur;
#pragma unroll
  for (int j = 0; j < 8; ++j) {
    int prj = __shfl(prCur, j);
    const float* src = x + (size_t)prj * 256 + ((l ^ j) << 2);
    load16_lds(src, &ldsx[0][(w * 8 + j) * 256]);
  }
  __syncthreads();  // vmcnt(0): prologue stage landed

  int buf = 0;
  int tCached = -1;
  bf16x8 wfr[32];  // W panel for current type: [kk*4+fn], 128 VGPRs
  const uint4* Wp4 = (const uint4*)Wp;
  // 16-float private slot; only [0,4) ever written (garbage sink). 256
  // threads x 16 floats = 16K floats = 64 KB region.
  float* dumpP = dump + (size_t)tid * 16;

  for (int it = 0; it < cnt; ++it) {
    int nrowsC = (int)(dscC.y >> 8);
    int tC = (int)(dscC.y & 15u);

    // A. stage tile it+1 into buf^1 (first in vmem queue)
    if (it + 1 < cnt) {
      if (l < 8) permS[buf ^ 1][w * 8 + l] = prNxt;
#pragma unroll
      for (int j = 0; j < 8; ++j) {
        int prj = __shfl(prNxt, j);
        const float* src = x + (size_t)prj * 256 + ((l ^ j) << 2);
        load16_lds(src, &ldsx[buf ^ 1][(w * 8 + j) * 256]);
      }
    }
    // B. register prefetch: perm for it+2, desc for it+3
    int prN2 = 0;
    if (it + 2 < cnt) {
      int nr2 = (int)(dscN2.y >> 8);
      if (myrow < nr2) prN2 = perm[dscN2.x + myrow];
    }
    int i3 = base + it + 3;
    uint2 dscN3 = desc[i3 <= clampT ? i3 : clampT];

    // W reload on type change (~1 per block + boundaries; uniform branch)
    if (tC != tCached) {
      tCached = tC;
      const uint4* Wt = Wp4 + (size_t)tC * 8 * 256 * 4;
#pragma unroll
      for (int kk = 0; kk < 8; kk++)
#pragma unroll
        for (int fn = 0; fn < 4; fn++)
          wfr[kk * 4 + fn] = __builtin_bit_cast(
              bf16x8, Wt[(size_t)(kk * 256 + w * 64 + fn * 16 + lm) * 4 + lh]);
    }

    // K-loop: pure LDS + VALU + MFMA (no vmem)
    f32x4 acc[2][4];
#pragma unroll
    for (int i = 0; i < 2; i++)
#pragma unroll
      for (int j = 0; j < 4; j++) acc[i][j] = (f32x4){0.f, 0.f, 0.f, 0.f};

#pragma unroll
    for (int kk = 0; kk < 8; kk++) {
      bf16x8 a[2];
#pragma unroll
      for (int fm = 0; fm < 2; fm++) {
        int r2 = fm * 16 + lm;
        const float4* rowp = (const float4*)&ldsx[buf][r2 * 256];
        int c0 = kk * 8 + lh * 2;
        int s = r2 & 7;
        float4 f0 = rowp[c0 ^ s];
        float4 f1 = rowp[(c0 + 1) ^ s];
        uint4 v;
        v.x = cvtpk(f0.x, f0.y);
        v.y = cvtpk(f0.z, f0.w);
        v.z = cvtpk(f1.x, f1.y);
        v.w = cvtpk(f1.z, f1.w);
        a[fm] = __builtin_bit_cast(bf16x8, v);
      }
#pragma unroll
      for (int fn = 0; fn < 4; fn++) {
        acc[0][fn] = __builtin_amdgcn_mfma_f32_16x16x32_bf16(
            a[0], wfr[kk * 4 + fn], acc[0][fn], 0, 0, 0);
        acc[1][fn] = __builtin_amdgcn_mfma_f32_16x16x32_bf16(
            a[1], wfr[kk * 4 + fn], acc[1][fn], 0, 0, 0);
      }
    }

    // stores: ALWAYS 32 per wave (branchless address select -> constant
    // vmem count); D layout col=lane&15, row=(lane>>4)*4+r_
#pragma unroll
    for (int fm = 0; fm < 2; fm++) {
#pragma unroll
      for (int r_ = 0; r_ < 4; r_++) {
        int rit = fm * 16 + lh * 4 + r_;
        bool valid = rit < nrowsC;
        int grow = permS[buf][rit & (TROWS - 1)];
        float* orow = out + (size_t)grow * 256 + w * 64 + lm;
#pragma unroll
        for (int fn = 0; fn < 4; fn++)
          __builtin_nontemporal_store(acc[fm][fn][r_],
                                      valid ? orow + fn * 16 : dumpP + fn);
      }
    }

    // counted barrier: retire stage (+perm,+W), leave stores in flight
    asm volatile("s_waitcnt vmcnt(32) lgkmcnt(0)\n\ts_barrier" ::: "memory");

    buf ^= 1;
    dscC = dscN;
    dscN = dscN2;
    dscN2 = dscN3;
    prCur = prNxt;
    prNxt = prN2;
  }
}

extern "C" void kernel_launch(void* const* d_in, const int* in_sizes, int n_in,
                              void* d_out, int out_size, void* d_ws,
                              size_t ws_size, hipStream_t stream) {
  const float* x = (const float*)d_in[0];
  const int* idx = (const int*)d_in[1];
  const float* W = (const float*)d_in[2];
  float* out = (float*)d_out;
  int N = in_sizes[0] / 256;
  int maxTiles = N / TROWS + NTYPES;

  // ws: meta 512B | dump 64KB | desc maxTiles*8 | perm N*4 | Wp 2MB
  unsigned int* meta = (unsigned int*)d_ws;
  float* dump = (float*)((char*)d_ws + 512);
  uint2* desc = (uint2*)((char*)d_ws + 512 + 65536);
  int* perm = (int*)((char*)d_ws + 512 + 65536 + (size_t)maxTiles * 8);
  unsigned short* Wp =
      (unsigned short*)((char*)d_ws + 512 + 65536 + (size_t)maxTiles * 8 +
                        (size_t)N * 4);

  zero_meta_kernel<<<1, 128, 0, stream>>>(meta);
  hist_kernel<<<256, 256, 0, stream>>>(idx, N, meta);
  prefix_kernel<<<1, 64, 0, stream>>>(meta);
  packW_kernel<<<128, 256, 0, stream>>>(W, Wp);
  tiles_kernel<<<(maxTiles + 255) / 256, 256, 0, stream>>>(meta, desc,
                                                           maxTiles);
  int nScatter = (N + 4095) / 4096;
  scatter_kernel<<<nScatter, 256, 0, stream>>>(idx, N, meta, perm);

  gemm_kernel<<<GRID_BLOCKS, 256, 0, stream>>>(x, Wp, perm, desc, out, dump,
                                               maxTiles);
}